// Round 6
// baseline (18.668 us; speedup 1.0000x reference)
//
#include <hip/hip_runtime.h>

constexpr int WIDTH     = 1000;
constexpr int HEIGHT    = 1000;
constexpr int N_PIXELS  = WIDTH * HEIGHT;
constexpr int PATCH     = 5;
constexpr int PATCHES_X = WIDTH / PATCH;      // 200
constexpr int BLOCK     = 64;                 // one wave per block
constexpr int MAXP      = BLOCK / PATCH + 3;  // 15 > max 14 patches per block

// PROBE ROUND: identical kernel launched TWICE to split fixed overhead from
// device time. T_dup - T_single = device_time + graph_node_cost.
__global__ __launch_bounds__(64) void ts_approx_kernel(
    const float* __restrict__ pix,      // [N, 2]
    const float* __restrict__ coef,     // [NUM_PATCHES, 3, 10, 2] = 60 floats/patch
    const float* __restrict__ bias,     // [NUM_PATCHES, 3]
    float* __restrict__ out)            // [3, N]
{
    __shared__ float scoef[MAXP * 60];
    __shared__ float sbias[MAXP * 3];

    const int tid  = threadIdx.x;
    const int prow = blockIdx.y;                               // patch row, 0..199
    const int c0   = blockIdx.x * BLOCK;
    const int p0   = c0 / PATCH;                               // uniform
    const int pend = min(c0 + BLOCK - 1, WIDTH - 1) / PATCH;   // uniform
    const int np   = pend - p0 + 1;                            // <= 14

    const float4* g4 = reinterpret_cast<const float4*>(coef + (size_t)(prow * PATCHES_X + p0) * 60);
    float4* s4 = reinterpret_cast<float4*>(scoef);
    const int nf4 = np * 15;
    for (int j = tid; j < nf4; j += BLOCK) s4[j] = g4[j];
    const float* gb = bias + (size_t)(prow * PATCHES_X + p0) * 3;
    for (int j = tid; j < np * 3; j += BLOCK) sbias[j] = gb[j];
    __syncthreads();

    const int col = c0 + tid;
    if (col >= WIDTH) return;

    const int row0 = prow * PATCH;
    const int pl   = col / PATCH - p0;

    float4 cf[15];
    const float4* c4 = reinterpret_cast<const float4*>(scoef + pl * 60);
    #pragma unroll
    for (int i = 0; i < 15; ++i) cf[i] = c4[i];
    const float b0 = sbias[pl * 3 + 0];
    const float b1 = sbias[pl * 3 + 1];
    const float b2 = sbias[pl * 3 + 2];

    const float2* p2 = reinterpret_cast<const float2*>(pix);

    float2 p[PATCH];
    #pragma unroll
    for (int r = 0; r < PATCH; ++r) p[r] = p2[(row0 + r) * WIDTH + col];

    #pragma unroll
    for (int r = 0; r < PATCH; ++r) {
        const float x = p[r].x, y = p[r].y;
        const int n = (row0 + r) * WIDTH + col;

        float res[3];
        #pragma unroll
        for (int c = 0; c < 3; ++c) {
            const int b = 5 * c;
            float hx = cf[b + 4].z;
            float hy = cf[b + 4].w;
            hx = fmaf(hx, x, cf[b + 4].x);  hy = fmaf(hy, y, cf[b + 4].y);
            hx = fmaf(hx, x, cf[b + 3].z);  hy = fmaf(hy, y, cf[b + 3].w);
            hx = fmaf(hx, x, cf[b + 3].x);  hy = fmaf(hy, y, cf[b + 3].y);
            hx = fmaf(hx, x, cf[b + 2].z);  hy = fmaf(hy, y, cf[b + 2].w);
            hx = fmaf(hx, x, cf[b + 2].x);  hy = fmaf(hy, y, cf[b + 2].y);
            hx = fmaf(hx, x, cf[b + 1].z);  hy = fmaf(hy, y, cf[b + 1].w);
            hx = fmaf(hx, x, cf[b + 1].x);  hy = fmaf(hy, y, cf[b + 1].y);
            hx = fmaf(hx, x, cf[b + 0].z);  hy = fmaf(hy, y, cf[b + 0].w);
            hx = fmaf(hx, x, cf[b + 0].x);  hy = fmaf(hy, y, cf[b + 0].y);
            res[c] = hx + hy;
        }
        out[0 * N_PIXELS + n] = res[0] + b0;
        out[1 * N_PIXELS + n] = res[1] + b1;
        out[2 * N_PIXELS + n] = res[2] + b2;
    }
}

extern "C" void kernel_launch(void* const* d_in, const int* in_sizes, int n_in,
                              void* d_out, int out_size, void* d_ws, size_t ws_size,
                              hipStream_t stream) {
    const float* pix  = (const float*)d_in[0];
    const float* coef = (const float*)d_in[1];
    const float* bias = (const float*)d_in[2];
    float* out = (float*)d_out;

    dim3 grid((WIDTH + BLOCK - 1) / BLOCK, HEIGHT / PATCH);   // (16, 200)
    // PROBE: launch twice. Second pass recomputes identical values and
    // overwrites the same output — deterministic, validation-safe.
    ts_approx_kernel<<<grid, BLOCK, 0, stream>>>(pix, coef, bias, out);
    ts_approx_kernel<<<grid, BLOCK, 0, stream>>>(pix, coef, bias, out);
}

// Round 8
// 13.073 us; speedup vs baseline: 1.4280x; 1.4280x over previous
//
#include <hip/hip_runtime.h>

constexpr int WIDTH     = 1000;
constexpr int HEIGHT    = 1000;
constexpr int N_PIXELS  = WIDTH * HEIGHT;
constexpr int PATCH     = 5;
constexpr int PATCHES_X = WIDTH / PATCH;      // 200
constexpr int BLOCK     = 64;                 // one wave per block
constexpr int MAXP      = BLOCK / PATCH + 3;  // 15 > max 14 patches per block

// native clang vector types: __builtin_nontemporal_* accepts these
typedef float vf4 __attribute__((ext_vector_type(4)));
typedef float vf2 __attribute__((ext_vector_type(2)));

// out[c, n] = sum_t sum_d coeff[patch(n), c, t, d] * pix[n, d]^t + bias[patch(n), c]
// Block (bx, py): 5-row band x 64 cols. Thread = one column: 5 vertical pixels
// in ONE patch; coef LDS->VGPR once per 5 pixels; Horner eval.
// All global traffic nontemporal: pix/out are touched exactly once device-wide
// -> don't let them evict the coef stream from L2/L3.
__global__ __launch_bounds__(64) void ts_approx_kernel(
    const float* __restrict__ pix,      // [N, 2]
    const float* __restrict__ coef,     // [NUM_PATCHES, 3, 10, 2] = 60 floats/patch
    const float* __restrict__ bias,     // [NUM_PATCHES, 3]
    float* __restrict__ out)            // [3, N]
{
    __shared__ float scoef[MAXP * 60];
    __shared__ float sbias[MAXP * 3];

    const int tid  = threadIdx.x;
    const int prow = blockIdx.y;                               // patch row, 0..199
    const int c0   = blockIdx.x * BLOCK;
    const int p0   = c0 / PATCH;                               // uniform
    const int pend = min(c0 + BLOCK - 1, WIDTH - 1) / PATCH;   // uniform
    const int np   = pend - p0 + 1;                            // <= 14

    // Stage this block's patch slice (contiguous, coalesced 16B, nt).
    const vf4* g4 = reinterpret_cast<const vf4*>(coef + (size_t)(prow * PATCHES_X + p0) * 60);
    vf4* s4 = reinterpret_cast<vf4*>(scoef);
    const int nf4 = np * 15;
    for (int j = tid; j < nf4; j += BLOCK) s4[j] = __builtin_nontemporal_load(&g4[j]);
    const float* gb = bias + (size_t)(prow * PATCHES_X + p0) * 3;
    for (int j = tid; j < np * 3; j += BLOCK) sbias[j] = __builtin_nontemporal_load(&gb[j]);
    __syncthreads();

    const int col = c0 + tid;
    if (col >= WIDTH) return;

    const int row0 = prow * PATCH;
    const int pl   = col / PATCH - p0;

    vf4 cf[15];
    const vf4* c4 = reinterpret_cast<const vf4*>(scoef + pl * 60);
    #pragma unroll
    for (int i = 0; i < 15; ++i) cf[i] = c4[i];
    const float b0 = sbias[pl * 3 + 0];
    const float b1 = sbias[pl * 3 + 1];
    const float b2 = sbias[pl * 3 + 2];

    const vf2* p2 = reinterpret_cast<const vf2*>(pix);

    vf2 p[PATCH];
    #pragma unroll
    for (int r = 0; r < PATCH; ++r)
        p[r] = __builtin_nontemporal_load(&p2[(row0 + r) * WIDTH + col]);

    #pragma unroll
    for (int r = 0; r < PATCH; ++r) {
        const float x = p[r].x, y = p[r].y;
        const int n = (row0 + r) * WIDTH + col;

        float res[3];
        #pragma unroll
        for (int c = 0; c < 3; ++c) {
            const int b = 5 * c;
            float hx = cf[b + 4].z;
            float hy = cf[b + 4].w;
            hx = fmaf(hx, x, cf[b + 4].x);  hy = fmaf(hy, y, cf[b + 4].y);
            hx = fmaf(hx, x, cf[b + 3].z);  hy = fmaf(hy, y, cf[b + 3].w);
            hx = fmaf(hx, x, cf[b + 3].x);  hy = fmaf(hy, y, cf[b + 3].y);
            hx = fmaf(hx, x, cf[b + 2].z);  hy = fmaf(hy, y, cf[b + 2].w);
            hx = fmaf(hx, x, cf[b + 2].x);  hy = fmaf(hy, y, cf[b + 2].y);
            hx = fmaf(hx, x, cf[b + 1].z);  hy = fmaf(hy, y, cf[b + 1].w);
            hx = fmaf(hx, x, cf[b + 1].x);  hy = fmaf(hy, y, cf[b + 1].y);
            hx = fmaf(hx, x, cf[b + 0].z);  hy = fmaf(hy, y, cf[b + 0].w);
            hx = fmaf(hx, x, cf[b + 0].x);  hy = fmaf(hy, y, cf[b + 0].y);
            res[c] = hx + hy;
        }
        __builtin_nontemporal_store(res[0] + b0, &out[0 * N_PIXELS + n]);
        __builtin_nontemporal_store(res[1] + b1, &out[1 * N_PIXELS + n]);
        __builtin_nontemporal_store(res[2] + b2, &out[2 * N_PIXELS + n]);
    }
}

extern "C" void kernel_launch(void* const* d_in, const int* in_sizes, int n_in,
                              void* d_out, int out_size, void* d_ws, size_t ws_size,
                              hipStream_t stream) {
    const float* pix  = (const float*)d_in[0];
    const float* coef = (const float*)d_in[1];
    const float* bias = (const float*)d_in[2];
    float* out = (float*)d_out;

    dim3 grid((WIDTH + BLOCK - 1) / BLOCK, HEIGHT / PATCH);   // (16, 200)
    ts_approx_kernel<<<grid, BLOCK, 0, stream>>>(pix, coef, bias, out);
}

// Round 9
// 11.614 us; speedup vs baseline: 1.6074x; 1.1256x over previous
//
#include <hip/hip_runtime.h>

constexpr int WIDTH     = 1000;
constexpr int HEIGHT    = 1000;
constexpr int N_PIXELS  = WIDTH * HEIGHT;
constexpr int PATCH     = 5;
constexpr int PATCHES_X = WIDTH / PATCH;      // 200
constexpr int BLOCK     = 256;
constexpr int MAXP      = BLOCK / PATCH + 2;  // 53 patches max per block

// out[c, n] = sum_t sum_d coeff[patch(n), c, t, d] * pix[n, d]^t + bias[patch(n), c]
// Block (bx, py): 5-row band [5*py, 5*py+5) x cols [bx*256, ...). Thread = one
// column of the band: 5 vertical pixels in ONE patch; coef LDS->VGPR once per
// 5 pixels; Horner evaluation (6 independent 9-fma chains per pixel).
// Default cache path: nt experiment (R7/R8) regressed 10% — L2 write-back
// helps the store stream. Best measured config (R4): 11.72 us.
__global__ __launch_bounds__(256) void ts_approx_kernel(
    const float* __restrict__ pix,      // [N, 2]
    const float* __restrict__ coef,     // [NUM_PATCHES, 3, 10, 2] = 60 floats/patch
    const float* __restrict__ bias,     // [NUM_PATCHES, 3]
    float* __restrict__ out)            // [3, N]
{
    __shared__ float scoef[MAXP * 60];
    __shared__ float sbias[MAXP * 3];

    const int tid  = threadIdx.x;
    const int prow = blockIdx.y;                               // patch row, 0..199
    const int c0   = blockIdx.x * BLOCK;
    const int p0   = c0 / PATCH;                               // uniform
    const int pend = min(c0 + BLOCK - 1, WIDTH - 1) / PATCH;   // uniform
    const int np   = pend - p0 + 1;                            // <= 52

    // Stage this block's patch slice (contiguous, coalesced float4).
    const float4* g4 = reinterpret_cast<const float4*>(coef + (size_t)(prow * PATCHES_X + p0) * 60);
    float4* s4 = reinterpret_cast<float4*>(scoef);
    const int nf4 = np * 15;
    for (int j = tid; j < nf4; j += BLOCK) s4[j] = g4[j];
    const float* gb = bias + (size_t)(prow * PATCHES_X + p0) * 3;
    for (int j = tid; j < np * 3; j += BLOCK) sbias[j] = gb[j];
    __syncthreads();

    const int col = c0 + tid;
    if (col >= WIDTH) return;

    const int row0 = prow * PATCH;
    const int pl   = col / PATCH - p0;             // local patch index

    // cf[i] = {c[2i,x], c[2i,y], c[2i+1,x], c[2i+1,y]}; i 0-4 ch0, 5-9 ch1, 10-14 ch2
    float4 cf[15];
    const float4* c4 = reinterpret_cast<const float4*>(scoef + pl * 60);
    #pragma unroll
    for (int i = 0; i < 15; ++i) cf[i] = c4[i];
    const float b0 = sbias[pl * 3 + 0];
    const float b1 = sbias[pl * 3 + 1];
    const float b2 = sbias[pl * 3 + 2];

    const float2* p2 = reinterpret_cast<const float2*>(pix);

    // preload all 5 pixel coords (independent loads issue together)
    float2 p[PATCH];
    #pragma unroll
    for (int r = 0; r < PATCH; ++r) p[r] = p2[(row0 + r) * WIDTH + col];

    #pragma unroll
    for (int r = 0; r < PATCH; ++r) {
        const float x = p[r].x, y = p[r].y;
        const int n = (row0 + r) * WIDTH + col;

        float res[3];
        #pragma unroll
        for (int c = 0; c < 3; ++c) {
            const int b = 5 * c;
            // Horner descending in t
            float hx = cf[b + 4].z;
            float hy = cf[b + 4].w;
            hx = fmaf(hx, x, cf[b + 4].x);  hy = fmaf(hy, y, cf[b + 4].y);
            hx = fmaf(hx, x, cf[b + 3].z);  hy = fmaf(hy, y, cf[b + 3].w);
            hx = fmaf(hx, x, cf[b + 3].x);  hy = fmaf(hy, y, cf[b + 3].y);
            hx = fmaf(hx, x, cf[b + 2].z);  hy = fmaf(hy, y, cf[b + 2].w);
            hx = fmaf(hx, x, cf[b + 2].x);  hy = fmaf(hy, y, cf[b + 2].y);
            hx = fmaf(hx, x, cf[b + 1].z);  hy = fmaf(hy, y, cf[b + 1].w);
            hx = fmaf(hx, x, cf[b + 1].x);  hy = fmaf(hy, y, cf[b + 1].y);
            hx = fmaf(hx, x, cf[b + 0].z);  hy = fmaf(hy, y, cf[b + 0].w);
            hx = fmaf(hx, x, cf[b + 0].x);  hy = fmaf(hy, y, cf[b + 0].y);
            res[c] = hx + hy;
        }
        out[0 * N_PIXELS + n] = res[0] + b0;
        out[1 * N_PIXELS + n] = res[1] + b1;
        out[2 * N_PIXELS + n] = res[2] + b2;
    }
}

extern "C" void kernel_launch(void* const* d_in, const int* in_sizes, int n_in,
                              void* d_out, int out_size, void* d_ws, size_t ws_size,
                              hipStream_t stream) {
    const float* pix  = (const float*)d_in[0];
    const float* coef = (const float*)d_in[1];
    const float* bias = (const float*)d_in[2];
    float* out = (float*)d_out;

    dim3 grid((WIDTH + BLOCK - 1) / BLOCK, HEIGHT / PATCH);   // (4, 200)
    ts_approx_kernel<<<grid, BLOCK, 0, stream>>>(pix, coef, bias, out);
}